// Round 5
// baseline (345.967 us; speedup 1.0000x reference)
//
#include <hip/hip_runtime.h>
#include <math.h>

#define N_NODES 100000
#define N_FEAT  256
#define K_SEL   50000
#define N_EDGES 3200000
#define NBUCKET 65536
#define NCHUNK  (NBUCKET / 256)

#define GATHER_BLOCKS (K_SEL / 4)           /* 4 rows (64 lanes ea) per 256-thr block */
#define EDGE_BLOCKS   (N_EDGES / (4 * 256)) /* 4 edges per thread */

// ---- key encodings -------------------------------------------------------
// ascending uint64 key == descending z, so stable-ascending == top_k order
__device__ __forceinline__ unsigned long long descKey(double z) {
    unsigned long long u = (unsigned long long)__double_as_longlong(z);
    unsigned long long a = (u >> 63) ? ~u : (u | 0x8000000000000000ULL);
    return ~a;
}

__device__ __forceinline__ unsigned int bucketOfFloat(float zf) {
    unsigned int u = __float_as_uint(zf);
    unsigned int a = (u >> 31) ? ~u : (u | 0x80000000u);
    return (~a) >> 16;
}

// ---- kernels -------------------------------------------------------------
// one wave per row: 64 lanes x float4 = 256 features, fp64 accumulate.
// ranking is monotone in the raw dot product -> no norm, no tanh here.
__global__ void score_kernel(const float* __restrict__ x, const float* __restrict__ w,
                             unsigned long long* __restrict__ key64,
                             float* __restrict__ dotf, int* __restrict__ hist) {
    int row  = (int)((blockIdx.x * blockDim.x + threadIdx.x) >> 6);
    int lane = threadIdx.x & 63;
    if (row >= N_NODES) return;
    const float4 xv = ((const float4*)(x + (size_t)row * N_FEAT))[lane];
    const float4 wv = ((const float4*)w)[lane];
    double acc = (double)xv.x * (double)wv.x + (double)xv.y * (double)wv.y +
                 (double)xv.z * (double)wv.z + (double)xv.w * (double)wv.w;
    for (int m = 32; m >= 1; m >>= 1) acc += __shfl_xor(acc, m, 64);
    if (lane == 0) {
        key64[row] = descKey(acc);
        float df = (float)acc;
        dotf[row] = df;
        atomicAdd(&hist[bucketOfFloat(df)], 1);
    }
}

// fused scan: per-chunk exclusive scan (256 blocks); the LAST block to finish
// (device-scope ticket, G16) additionally scans the 256 chunk sums into offs
// and computes 1/||w||. Removes a 1-block kernel from the critical path.
__global__ void scanAB_kernel(const int* __restrict__ hist, int* __restrict__ partial,
                              int* __restrict__ chunkSum, int* __restrict__ offs,
                              const float* __restrict__ w, float* __restrict__ invNorm,
                              int* __restrict__ doneCount) {
    __shared__ int tmp[256];
    __shared__ int lastTicket;
    int t = threadIdx.x;
    int g = blockIdx.x * 256 + t;
    int v = hist[g];
    tmp[t] = v;
    __syncthreads();
    for (int off = 1; off < 256; off <<= 1) {
        int u = (t >= off) ? tmp[t - off] : 0;
        __syncthreads();
        tmp[t] += u;
        __syncthreads();
    }
    partial[g] = tmp[t] - v;                 // exclusive within chunk
    if (t == 255) chunkSum[blockIdx.x] = tmp[255];
    // release chunkSum device-wide, then take a ticket
    __threadfence();
    if (t == 0) lastTicket = atomicAdd(doneCount, 1);
    __syncthreads();
    if (lastTicket != NCHUNK - 1) return;
    // ---- last block: scan chunk sums + ||w|| ----
    __threadfence();                         // acquire other blocks' chunkSum
    __shared__ double sd[256];
    int cv = chunkSum[t];
    tmp[t] = cv;
    double wv = (double)w[t];
    sd[t] = wv * wv;
    __syncthreads();
    for (int off = 1; off < 256; off <<= 1) {
        int u = (t >= off) ? tmp[t - off] : 0;
        __syncthreads();
        tmp[t] += u;
        __syncthreads();
    }
    offs[t] = tmp[t] - cv;                   // exclusive chunk offset
    for (int off = 128; off > 0; off >>= 1) {
        if (t < off) sd[t] += sd[t + off];
        __syncthreads();
    }
    if (t == 0) invNorm[0] = (float)(1.0 / sqrt(sd[0]));
}

// scatter nodes into bucket slot ranges: pos = chunk offset + within-chunk
// prefix (partial, consumed via atomicAdd)
__global__ void scatter_kernel(const unsigned long long* __restrict__ key64,
                               const float* __restrict__ dotf,
                               const int* __restrict__ offs, int* __restrict__ partial,
                               unsigned long long* __restrict__ slotKey,
                               int* __restrict__ slotIdx) {
    int i = blockIdx.x * blockDim.x + threadIdx.x;
    if (i >= N_NODES) return;
    int b = (int)bucketOfFloat(dotf[i]);
    int pos = offs[b >> 8] + atomicAdd(&partial[b], 1);
    slotKey[pos] = key64[i];
    slotIdx[pos] = i;
}

// exact rank within bucket via fp64 key + index tie-break.
// post-scatter: bucket end = offs[b>>8] + partial[b]; begin = end - hist[b].
__global__ void rank_kernel(const unsigned long long* __restrict__ slotKey,
                            const int* __restrict__ slotIdx,
                            const int* __restrict__ offs, const int* __restrict__ partial,
                            const int* __restrict__ hist,
                            const float* __restrict__ dotf,
                            unsigned short* __restrict__ mapping16,
                            int* __restrict__ perm, float* __restrict__ selDot) {
    int s = blockIdx.x * blockDim.x + threadIdx.x;
    if (s >= N_NODES) return;
    unsigned long long myKey = slotKey[s];
    int i = slotIdx[s];
    float df = dotf[i];
    int b = (int)bucketOfFloat(df);
    int end = offs[b >> 8] + partial[b];
    int cnt = hist[b];
    int st = end - cnt;
    int rank = 0;
    for (int t = st; t < end; ++t) {
        unsigned long long k = slotKey[t];
        if (k < myKey || (k == myKey && slotIdx[t] < i)) ++rank;
    }
    int p = st + rank;
    if (p < K_SEL) {
        mapping16[i] = (unsigned short)p;
        perm[p] = i;
        selDot[p] = df;
    } else {
        mapping16[i] = 0xFFFFu;
    }
}

// fused output: blocks [0,GATHER_BLOCKS) gather+gate x rows (tanh here, fp32,
// selected rows only); blocks [GATHER_BLOCKS,...) remap edges, 4/thread int4
__global__ void out_kernel(const float* __restrict__ x, const int* __restrict__ perm,
                           const float* __restrict__ selDot,
                           const float* __restrict__ invNormp,
                           const int* __restrict__ ei,
                           const unsigned short* __restrict__ mapping16,
                           float* __restrict__ out) {
    if (blockIdx.x < GATHER_BLOCKS) {
        int tid = blockIdx.x * 256 + threadIdx.x;
        int r = tid >> 6;
        int c = (tid & 63) << 2;
        int src = perm[r];
        float sc = tanhf(selDot[r] * invNormp[0]);
        float4 v = *(const float4*)(x + (size_t)src * N_FEAT + c);
        float4 o;
        o.x = v.x * sc; o.y = v.y * sc; o.z = v.z * sc; o.w = v.w * sc;
        *(float4*)(out + (size_t)r * N_FEAT + c) = o;
    } else {
        int tid = (blockIdx.x - GATHER_BLOCKS) * 256 + threadIdx.x;
        int e = tid << 2;
        int4 a = *(const int4*)(ei + e);
        int4 b = *(const int4*)(ei + N_EDGES + e);
        float* oeu = out + (size_t)K_SEL * N_FEAT;
        float* oev = oeu + N_EDGES;
        unsigned short m0 = mapping16[a.x], m1 = mapping16[a.y];
        unsigned short m2 = mapping16[a.z], m3 = mapping16[a.w];
        unsigned short n0 = mapping16[b.x], n1 = mapping16[b.y];
        unsigned short n2 = mapping16[b.z], n3 = mapping16[b.w];
        bool v0 = (m0 != 0xFFFFu) && (n0 != 0xFFFFu);
        bool v1 = (m1 != 0xFFFFu) && (n1 != 0xFFFFu);
        bool v2 = (m2 != 0xFFFFu) && (n2 != 0xFFFFu);
        bool v3 = (m3 != 0xFFFFu) && (n3 != 0xFFFFu);
        float4 ou, ov;
        ou.x = v0 ? (float)m0 : -1.0f; ov.x = v0 ? (float)n0 : -1.0f;
        ou.y = v1 ? (float)m1 : -1.0f; ov.y = v1 ? (float)n1 : -1.0f;
        ou.z = v2 ? (float)m2 : -1.0f; ov.z = v2 ? (float)n2 : -1.0f;
        ou.w = v3 ? (float)m3 : -1.0f; ov.w = v3 ? (float)n3 : -1.0f;
        *(float4*)(oeu + e) = ou;
        *(float4*)(oev + e) = ov;
    }
}

// ---- launch --------------------------------------------------------------
extern "C" void kernel_launch(void* const* d_in, const int* in_sizes, int n_in,
                              void* d_out, int out_size, void* d_ws, size_t ws_size,
                              hipStream_t stream) {
    const float* x  = (const float*)d_in[0];
    const int*   ei = (const int*)d_in[1];
    const float* w  = (const float*)d_in[2];
    float* out = (float*)d_out;

    // every allocation is a multiple of 16 bytes -> all pointers 16-aligned
    char* p = (char*)d_ws;
    float* d_invNorm = (float*)p;                         p += 16;
    unsigned long long* key64   = (unsigned long long*)p; p += (size_t)N_NODES * 8;
    unsigned long long* slotKey = (unsigned long long*)p; p += (size_t)N_NODES * 8;
    float* dotf   = (float*)p;  p += (size_t)N_NODES * 4;
    int*   slotIdx= (int*)p;    p += (size_t)N_NODES * 4;
    unsigned short* mapping16 = (unsigned short*)p;       p += (size_t)N_NODES * 2; // 200000 % 16 == 0
    int*   perm   = (int*)p;    p += (size_t)K_SEL * 4;
    float* selDot = (float*)p;  p += (size_t)K_SEL * 4;
    int*   hist   = (int*)p;    p += (size_t)NBUCKET * 4;
    int*   doneCount = (int*)p; p += 16;                  // adjacent to hist: one memset
    int*   partial= (int*)p;    p += (size_t)NBUCKET * 4;
    int*   chunkSum=(int*)p;    p += (size_t)NCHUNK * 4;
    int*   offs   = (int*)p;    p += (size_t)NCHUNK * 4;

    // zero hist + doneCount in one fill
    hipMemsetAsync(hist, 0, (size_t)NBUCKET * 4 + 16, stream);

    int waves_blocks = (N_NODES * 64 + 255) / 256;
    score_kernel<<<waves_blocks, 256, 0, stream>>>(x, w, key64, dotf, hist);

    scanAB_kernel<<<NCHUNK, 256, 0, stream>>>(hist, partial, chunkSum, offs,
                                              w, d_invNorm, doneCount);

    int node_blocks = (N_NODES + 255) / 256;
    scatter_kernel<<<node_blocks, 256, 0, stream>>>(key64, dotf, offs, partial,
                                                    slotKey, slotIdx);

    rank_kernel<<<node_blocks, 256, 0, stream>>>(slotKey, slotIdx, offs, partial, hist,
                                                 dotf, mapping16, perm, selDot);

    out_kernel<<<GATHER_BLOCKS + EDGE_BLOCKS, 256, 0, stream>>>(x, perm, selDot,
                                                                d_invNorm, ei,
                                                                mapping16, out);
}

// Round 6
// 318.740 us; speedup vs baseline: 1.0854x; 1.0854x over previous
//
#include <hip/hip_runtime.h>
#include <math.h>

#define N_NODES 100000
#define N_FEAT  256
#define K_SEL   50000
#define N_EDGES 3200000
#define NBUCKET 65536

#define GATHER_BLOCKS (K_SEL / 4)           /* 4 rows (64 lanes ea) per 256-thr block */
#define EDGE_BLOCKS   (N_EDGES / (4 * 256)) /* 4 edges per thread */

// ---- key encodings -------------------------------------------------------
// ascending uint64 key == descending z, so stable-ascending == top_k order
__device__ __forceinline__ unsigned long long descKey(double z) {
    unsigned long long u = (unsigned long long)__double_as_longlong(z);
    unsigned long long a = (u >> 63) ? ~u : (u | 0x8000000000000000ULL);
    return ~a;
}

__device__ __forceinline__ unsigned int bucketOfFloat(float zf) {
    unsigned int u = __float_as_uint(zf);
    unsigned int a = (u >> 31) ? ~u : (u | 0x80000000u);
    return (~a) >> 16;
}

// ---- kernels -------------------------------------------------------------
// zero hist (65536 ints, 1/thread) + block 0 computes ||w|| in fp64
__global__ void init_kernel(const float* __restrict__ w, double* __restrict__ norm,
                            int* __restrict__ hist) {
    __shared__ double sd[256];
    int t = blockIdx.x * blockDim.x + threadIdx.x;
    hist[t] = 0;
    if (blockIdx.x == 0) {
        int tt = threadIdx.x;
        double v = (double)w[tt];
        sd[tt] = v * v;
        __syncthreads();
        for (int off = 128; off > 0; off >>= 1) {
            if (tt < off) sd[tt] += sd[tt + off];
            __syncthreads();
        }
        if (tt == 0) norm[0] = sqrt(sd[0]);
    }
}

// one wave per row: 64 lanes x float4 = 256 features, fp64 accumulate.
// ranking is monotone in the raw dot product -> no norm, no tanh here.
__global__ void score_kernel(const float* __restrict__ x, const float* __restrict__ w,
                             unsigned long long* __restrict__ key64,
                             float* __restrict__ dotf, int* __restrict__ hist) {
    int row  = (int)((blockIdx.x * blockDim.x + threadIdx.x) >> 6);
    int lane = threadIdx.x & 63;
    if (row >= N_NODES) return;
    const float4 xv = ((const float4*)(x + (size_t)row * N_FEAT))[lane];
    const float4 wv = ((const float4*)w)[lane];
    double acc = (double)xv.x * (double)wv.x + (double)xv.y * (double)wv.y +
                 (double)xv.z * (double)wv.z + (double)xv.w * (double)wv.w;
    for (int m = 32; m >= 1; m >>= 1) acc += __shfl_xor(acc, m, 64);
    if (lane == 0) {
        key64[row] = descKey(acc);
        float df = (float)acc;
        dotf[row] = df;
        atomicAdd(&hist[bucketOfFloat(df)], 1);
    }
}

// exclusive prefix over 65536 bins; single block, int4-vectorized
__global__ void __launch_bounds__(1024) scan_kernel(const int4* __restrict__ hist4,
                                                    int* __restrict__ start) {
    __shared__ int sums[1024];
    int t = threadIdx.x;
    int4 v[16];
#pragma unroll
    for (int j = 0; j < 16; ++j) v[j] = hist4[t * 16 + j];
    int s = 0;
#pragma unroll
    for (int j = 0; j < 16; ++j) { s += v[j].x + v[j].y + v[j].z + v[j].w; }
    sums[t] = s;
    __syncthreads();
    for (int off = 1; off < 1024; off <<= 1) {
        int vv = (t >= off) ? sums[t - off] : 0;
        __syncthreads();
        sums[t] += vv;
        __syncthreads();
    }
    int run = (t == 0) ? 0 : sums[t - 1];
    int4* start4 = (int4*)start;
#pragma unroll
    for (int j = 0; j < 16; ++j) {
        int4 o;
        o.x = run; run += v[j].x;
        o.y = run; run += v[j].y;
        o.z = run; run += v[j].z;
        o.w = run; run += v[j].w;
        start4[t * 16 + j] = o;
    }
}

// scatter nodes to their bucket's slot range; consumes start[] via atomicAdd
__global__ void scatter_kernel(const unsigned long long* __restrict__ key64,
                               const float* __restrict__ dotf,
                               int* __restrict__ start,
                               unsigned long long* __restrict__ slotKey,
                               int* __restrict__ slotIdx) {
    int i = blockIdx.x * blockDim.x + threadIdx.x;
    if (i >= N_NODES) return;
    int b = (int)bucketOfFloat(dotf[i]);
    int pos = atomicAdd(&start[b], 1);
    slotKey[pos] = key64[i];
    slotIdx[pos] = i;
}

// exact rank within bucket via fp64 key + index tie-break.
// post-scatter start[b] == bucket end; begin = end - hist[b].
__global__ void rank_kernel(const unsigned long long* __restrict__ slotKey,
                            const int* __restrict__ slotIdx,
                            const int* __restrict__ start, const int* __restrict__ hist,
                            const float* __restrict__ dotf,
                            int* __restrict__ mapping, int* __restrict__ perm,
                            float* __restrict__ selDot) {
    int s = blockIdx.x * blockDim.x + threadIdx.x;
    if (s >= N_NODES) return;
    unsigned long long myKey = slotKey[s];
    int i = slotIdx[s];
    float df = dotf[i];
    int b = (int)bucketOfFloat(df);
    int end = start[b];
    int cnt = hist[b];
    int st = end - cnt;
    int rank = 0;
    for (int t = st; t < end; ++t) {
        unsigned long long k = slotKey[t];
        if (k < myKey || (k == myKey && slotIdx[t] < i)) ++rank;
    }
    int p = st + rank;
    if (p < K_SEL) {
        mapping[i] = p;
        perm[p] = i;
        selDot[p] = df;
    } else {
        mapping[i] = -1;
    }
}

// fused output: blocks [0,GATHER_BLOCKS) gather+gate x rows (tanh here, fp32,
// selected rows only); blocks [GATHER_BLOCKS,...) remap edges, 4/thread int4
__global__ void out_kernel(const float* __restrict__ x, const int* __restrict__ perm,
                           const float* __restrict__ selDot,
                           const double* __restrict__ normp,
                           const int* __restrict__ ei, const int* __restrict__ mapping,
                           float* __restrict__ out) {
    if (blockIdx.x < GATHER_BLOCKS) {
        int tid = blockIdx.x * 256 + threadIdx.x;
        int r = tid >> 6;
        int c = (tid & 63) << 2;
        int src = perm[r];
        float sc = tanhf(selDot[r] / (float)normp[0]);
        float4 v = *(const float4*)(x + (size_t)src * N_FEAT + c);
        float4 o;
        o.x = v.x * sc; o.y = v.y * sc; o.z = v.z * sc; o.w = v.w * sc;
        *(float4*)(out + (size_t)r * N_FEAT + c) = o;
    } else {
        int tid = (blockIdx.x - GATHER_BLOCKS) * 256 + threadIdx.x;
        int e = tid << 2;
        int4 a = *(const int4*)(ei + e);
        int4 b = *(const int4*)(ei + N_EDGES + e);
        float* oeu = out + (size_t)K_SEL * N_FEAT;
        float* oev = oeu + N_EDGES;
        int m0 = mapping[a.x], m1 = mapping[a.y], m2 = mapping[a.z], m3 = mapping[a.w];
        int n0 = mapping[b.x], n1 = mapping[b.y], n2 = mapping[b.z], n3 = mapping[b.w];
        float4 ou, ov;
        bool v0 = (m0 >= 0) && (n0 >= 0);
        bool v1 = (m1 >= 0) && (n1 >= 0);
        bool v2 = (m2 >= 0) && (n2 >= 0);
        bool v3 = (m3 >= 0) && (n3 >= 0);
        ou.x = v0 ? (float)m0 : -1.0f; ov.x = v0 ? (float)n0 : -1.0f;
        ou.y = v1 ? (float)m1 : -1.0f; ov.y = v1 ? (float)n1 : -1.0f;
        ou.z = v2 ? (float)m2 : -1.0f; ov.z = v2 ? (float)n2 : -1.0f;
        ou.w = v3 ? (float)m3 : -1.0f; ov.w = v3 ? (float)n3 : -1.0f;
        *(float4*)(oeu + e) = ou;
        *(float4*)(oev + e) = ov;
    }
}

// ---- launch --------------------------------------------------------------
extern "C" void kernel_launch(void* const* d_in, const int* in_sizes, int n_in,
                              void* d_out, int out_size, void* d_ws, size_t ws_size,
                              hipStream_t stream) {
    const float* x  = (const float*)d_in[0];
    const int*   ei = (const int*)d_in[1];
    const float* w  = (const float*)d_in[2];
    float* out = (float*)d_out;

    char* p = (char*)d_ws;
    double* d_norm = (double*)p;                          p += 16;
    unsigned long long* key64   = (unsigned long long*)p; p += (size_t)N_NODES * 8;
    unsigned long long* slotKey = (unsigned long long*)p; p += (size_t)N_NODES * 8;
    float* dotf   = (float*)p;  p += (size_t)N_NODES * 4;
    int*   mapping= (int*)p;    p += (size_t)N_NODES * 4;
    int*   slotIdx= (int*)p;    p += (size_t)N_NODES * 4;
    int*   perm   = (int*)p;    p += (size_t)K_SEL * 4;
    float* selDot = (float*)p;  p += (size_t)K_SEL * 4;
    int*   hist   = (int*)p;    p += (size_t)NBUCKET * 4;
    int*   start  = (int*)p;    p += (size_t)NBUCKET * 4;

    init_kernel<<<NBUCKET / 256, 256, 0, stream>>>(w, d_norm, hist);

    int waves_blocks = (N_NODES * 64 + 255) / 256;
    score_kernel<<<waves_blocks, 256, 0, stream>>>(x, w, key64, dotf, hist);

    scan_kernel<<<1, 1024, 0, stream>>>((const int4*)hist, start);

    int node_blocks = (N_NODES + 255) / 256;
    scatter_kernel<<<node_blocks, 256, 0, stream>>>(key64, dotf, start, slotKey, slotIdx);

    rank_kernel<<<node_blocks, 256, 0, stream>>>(slotKey, slotIdx, start, hist, dotf,
                                                 mapping, perm, selDot);

    out_kernel<<<GATHER_BLOCKS + EDGE_BLOCKS, 256, 0, stream>>>(x, perm, selDot, d_norm,
                                                                ei, mapping, out);
}